// Round 8
// baseline (1325.480 us; speedup 1.0000x reference)
//
#include <hip/hip_runtime.h>

// GRNN scan: B=512 sequences, T=8192 steps. Round 18.
// R17 post-mortem: packed math helped per-row (182 vs 246 cyc/row-granule)
// but 4 blocks halved active CUs -> net regression. KEY FIND: VGPR=84-88
// across R12-R17 proves the dy/W register rings were NEVER live - compiler
// sinks ring loads to point-of-use (SSA locals don't pin liveness), so every
// granule eats a raw ds/L2 round trip (~123 cyc/step invariant). R15's 213
// was global_load_lds being the one un-sinkable prefetch.
// R18: R16 structure (8 blocks, fused producer) + R17 packed consumer math
// (1 row/lane) + asm volatile("" : "+v"(reg)) PINS after every ring load
// (W sets + dy reloads) - forces loads issued early + values held live ->
// true prefetch. Diagnostic: VGPR_Count >= 140 means rings are live.

#define DT_C 1e-3f
#define MAXU 0.1f
#define T_LEN 8192
#define T4 (T_LEN / 2)          // 4096 float4 granules (2 steps each)
#define CHUNK 256               // steps per chunk
#define G_CHUNK (CHUNK / 2)     // 128 granules per chunk
#define NCHUNK (T_LEN / CHUNK)  // 32
#define BROWS 512               // batch rows

typedef float f2 __attribute__((ext_vector_type(2)));
typedef float f4v __attribute__((ext_vector_type(4)));

__device__ __forceinline__ float clipf(float v, float lo, float hi) {
    return fminf(fmaxf(v, lo), hi);
}
__device__ __forceinline__ f2 pkfma(f2 a, f2 b, f2 c) {
    return __builtin_elementwise_fma(a, b, c);
}
__device__ __forceinline__ f2 pkclip(f2 v) {
    const f2 lo = {-MAXU, -MAXU}, hi = {MAXU, MAXU};
    return __builtin_elementwise_min(__builtin_elementwise_max(v, lo), hi);
}
#define SB() __builtin_amdgcn_sched_barrier(0)

// ---------------- tiled float4 transpose: src[rows][cols] -> dst[cols][rows]
__global__ __launch_bounds__(256) void transpose_f4(
    const float4* __restrict__ src, float4* __restrict__ dst,
    int rows, int cols)
{
    __shared__ float4 tile[32][33];
    const int tx = threadIdx.x & 31;
    const int ty = threadIdx.x >> 5;
    const int c0 = blockIdx.x * 32;
    const int r0 = blockIdx.y * 32;
#pragma unroll
    for (int i = 0; i < 32; i += 8)
        tile[ty + i][tx] = src[(size_t)(r0 + ty + i) * cols + (c0 + tx)];
    __syncthreads();
#pragma unroll
    for (int i = 0; i < 32; i += 8)
        dst[(size_t)(c0 + ty + i) * rows + (r0 + tx)] = tile[tx][ty + i];
}

// ============= fused scan: wave0 consumer (pinned rings), wave1 producer ==
// inT/outT are [T4][BROWS] float4 (transposed layout, proven R12).
__global__ __launch_bounds__(128, 1) void grnn_fused4(
    const float4* __restrict__ inT, const float* __restrict__ Am,
    const float* __restrict__ Cm, const float* __restrict__ Dm,
    float4* __restrict__ outT)
{
    __shared__ float4 wlds[2][CHUNK * 2];   // 16 KB W double buffer
    __shared__ float4 sbnd[CHUNK / 8];      // 32 sub-boundaries (every 8 steps)
    const int tid = threadIdx.x;
    const int wv = tid >> 6;

    if (wv == 1) {
        // ===================== producer wave (unchanged R16) =============
        const int lane = tid & 63;
        const float a00 = Am[0], a01 = Am[1], a10 = Am[2], a11 = Am[3];
        const float c00 = Cm[0], c01 = Cm[1], c10 = Cm[2], c11 = Cm[3];
        const float d00 = Dm[0], d01 = Dm[1], d10 = Dm[2], d11 = Dm[3];
        const bool special = (c00 == 1.f) && (c01 == 0.f) && (c10 == 0.f) &&
                             (c11 == 1.f) && (d01 == 0.f) && (d10 == 0.f);
        const float adt00 = a00 * DT_C, adt01 = a01 * DT_C;
        const float adt10 = a10 * DT_C, adt11 = a11 * DT_C;

        if (special) {
            // xi-space: u=p00+d00, w=p01, v=p11+d11 (== RSTEP_S algebra)
            const float K00 = 1.f + 2.f * adt00, A2dt01 = 2.f * adt01;
            const float K11 = 1.f + 2.f * adt11, A2dt10 = 2.f * adt10;
            const float K01 = 1.f + (a00 + a11) * DT_C;
            const float C0u = DT_C * d00 * (1.f - 2.f * a00);
            const float C0v = DT_C * d11 * (1.f - 2.f * a11);
            const float C1w = -(adt10 * d00 + adt01 * d11);

#define XSTEP()                                                               \
            {                                                                 \
                const float w2 = w * w;                                       \
                const float gu = fmaf(-DT_C, u, K00);                         \
                const float gv = fmaf(-DT_C, v, K11);                         \
                const float s  = u + v;                                       \
                const float ru = fmaf(A2dt01, w, fmaf(-DT_C, w2, C0u));       \
                const float rv = fmaf(A2dt10, w, fmaf(-DT_C, w2, C0v));       \
                const float gw = fmaf(-DT_C, s, K01);                         \
                const float rw = fmaf(adt10, u, fmaf(adt01, v, C1w));         \
                const float un = fmaf(u, gu, ru);                             \
                const float vn = fmaf(v, gv, rv);                             \
                const float wn = fmaf(w, gw, rw);                             \
                u = un; v = vn; w = wn;                                       \
            }

            float u = 1.f + d00, w = 0.f, v = 1.f + d11;  // P0=I
            for (int it = 0; it <= NCHUNK; ++it) {
                if (it < NCHUNK) {
                    if (lane == 0) {
                        for (int j = 0; j < CHUNK / 8; ++j) {
                            sbnd[j] = make_float4(u, w, v, 0.f);
                            XSTEP() XSTEP() XSTEP() XSTEP()
                            XSTEP() XSTEP() XSTEP() XSTEP()
                        }
                    }
                    asm volatile("s_waitcnt lgkmcnt(0)" ::: "memory");
                    SB();
                    __builtin_amdgcn_wave_barrier();
                    if (lane < CHUNK / 8) {
                        const float4 sb = sbnd[lane];
                        float u2 = sb.x, w2v = sb.y, v2 = sb.z;
                        float4* wdst = wlds[it & 1] + 2 * (lane * 8);
#pragma unroll
                        for (int k = 0; k < 8; ++k) {
                            float4 mv, xv;
                            mv.x = fmaf(-DT_C, u2, adt00);
                            mv.y = fmaf(-DT_C, w2v, adt10);
                            mv.z = fmaf(-DT_C, w2v, adt01);
                            mv.w = fmaf(-DT_C, v2, adt11);
                            xv = make_float4(u2, w2v, w2v, v2);
                            wdst[2 * k]     = mv;
                            wdst[2 * k + 1] = xv;
                            {
                                float u = u2, w = w2v, v = v2;
                                XSTEP()
                                u2 = u; w2v = w; v2 = v;
                            }
                        }
                    }
                }
                __syncthreads();
            }
#undef XSTEP
        } else {
            // generic path: full P, clips kept
#define RSTEP_G()                                                             \
            {                                                                 \
                const float xi00 = p00*c00 + p01*c01 + d00;                   \
                const float xi01 = p00*c10 + p01*c11 + d10;                   \
                const float xi10 = p10*c00 + p11*c01 + d01;                   \
                const float xi11 = p10*c10 + p11*c11 + d11;                   \
                const float g00 = a00*p00 + a01*p10 + p00*a00 + p01*a01 + d00 - (xi00*xi00 + xi01*xi01); \
                const float g01 = a00*p01 + a01*p11 + p00*a10 + p01*a11 + d01 - (xi00*xi10 + xi01*xi11); \
                const float g10 = a10*p00 + a11*p10 + p10*a00 + p11*a01 + d10 - (xi10*xi00 + xi11*xi01); \
                const float g11 = a10*p01 + a11*p11 + p10*a10 + p11*a11 + d11 - (xi10*xi10 + xi11*xi11); \
                p00 = clipf(p00 + g00 * DT_C, -1.f, 1.f);                     \
                p01 = clipf(p01 + g01 * DT_C, -1.f, 1.f);                     \
                p10 = clipf(p10 + g10 * DT_C, -1.f, 1.f);                     \
                p11 = clipf(p11 + g11 * DT_C, -1.f, 1.f);                     \
            }
            float p00 = 1.f, p01 = 0.f, p10 = 0.f, p11 = 1.f;
            for (int it = 0; it <= NCHUNK; ++it) {
                if (it < NCHUNK) {
                    if (lane == 0) {
                        for (int j = 0; j < CHUNK / 8; ++j) {
                            sbnd[j] = make_float4(p00, p01, p10, p11);
                            RSTEP_G() RSTEP_G() RSTEP_G() RSTEP_G()
                            RSTEP_G() RSTEP_G() RSTEP_G() RSTEP_G()
                        }
                    }
                    asm volatile("s_waitcnt lgkmcnt(0)" ::: "memory");
                    SB();
                    __builtin_amdgcn_wave_barrier();
                    if (lane < CHUNK / 8) {
                        const float4 sb = sbnd[lane];
                        float p00 = sb.x, p01 = sb.y, p10 = sb.z, p11 = sb.w;
                        float4* wdst = wlds[it & 1] + 2 * (lane * 8);
#pragma unroll
                        for (int k = 0; k < 8; ++k) {
                            const float xi00 = p00*c00 + p01*c01 + d00;
                            const float xi01 = p00*c10 + p01*c11 + d10;
                            const float xi10 = p10*c00 + p11*c01 + d01;
                            const float xi11 = p10*c10 + p11*c11 + d11;
                            const float m00 = a00 - (xi00*c00 + xi01*c10);
                            const float m01 = a01 - (xi00*c01 + xi01*c11);
                            const float m10 = a10 - (xi10*c00 + xi11*c10);
                            const float m11 = a11 - (xi10*c01 + xi11*c11);
                            float4 mv, xv;
                            mv.x = m00 * DT_C; mv.y = m10 * DT_C;
                            mv.z = m01 * DT_C; mv.w = m11 * DT_C;
                            xv = make_float4(xi00, xi10, xi01, xi11);
                            wdst[2 * k]     = mv;
                            wdst[2 * k + 1] = xv;
                            RSTEP_G()
                        }
                    }
                }
                __syncthreads();
            }
#undef RSTEP_G
        }
    } else {
        // ======= consumer wave: 1 row/lane, packed math, PINNED rings ====
        const int lane = tid;
        const int b = blockIdx.x * 64 + lane;
        const f2 CC0 = {Cm[0] * DT_C, Cm[2] * DT_C};   // C column 0 * dt
        const f2 CC1 = {Cm[1] * DT_C, Cm[3] * DT_C};   // C column 1 * dt
        const f4v* __restrict__ inTv = reinterpret_cast<const f4v*>(inT);
        f4v* __restrict__ outTv = reinterpret_cast<f4v*>(outT);

        f2 X = {1.f, 0.f};
        // dy ring: 8-granule lookahead, PINNED live after each load
        f4v d0 = inTv[(size_t)0 * BROWS + b], d1 = inTv[(size_t)1 * BROWS + b];
        f4v d2 = inTv[(size_t)2 * BROWS + b], d3 = inTv[(size_t)3 * BROWS + b];
        f4v d4 = inTv[(size_t)4 * BROWS + b], d5 = inTv[(size_t)5 * BROWS + b];
        f4v d6 = inTv[(size_t)6 * BROWS + b], d7 = inTv[(size_t)7 * BROWS + b];
        asm volatile("" : "+v"(d0), "+v"(d1), "+v"(d2), "+v"(d3));
        asm volatile("" : "+v"(d4), "+v"(d5), "+v"(d6), "+v"(d7));
        // W ring: 4 sets, PINNED live after each load
        f4v s0a, s0b, s0c, s0d, s1a, s1b, s1c, s1d;
        f4v t0a, t0b, t0c, t0d, t1a, t1b, t1c, t1d;

#define WLG(P, G)                                                             \
        {                                                                     \
            const int gg = (G) < G_CHUNK ? (G) : (G_CHUNK - 1);               \
            const f4v* wp = reinterpret_cast<const f4v*>(wbuf + 4 * gg);      \
            P##a = wp[0]; P##b = wp[1]; P##c = wp[2]; P##d = wp[3];           \
            asm volatile("" : "+v"(P##a), "+v"(P##b), "+v"(P##c),             \
                             "+v"(P##d));                                     \
        }

        // one granule = 2 steps. P##a/c = Mdt step0/1, P##b/d = Xi step0/1.
#define GRANC(P, DJ, OG)                                                      \
        {                                                                     \
            const f4v yv = DJ;                                                \
            {                                                                 \
                const int nog = (OG) + 8;                                     \
                const int rg = nog < T4 ? nog : (T4 - 1);                     \
                DJ = inTv[(size_t)rg * BROWS + b];                            \
                asm volatile("" : "+v"(DJ));                                  \
            }                                                                 \
            const f2 ma0 = P##a.xy, ma1 = P##a.zw;                            \
            const f2 xb0 = P##b.xy, xb1 = P##b.zw;                            \
            const f2 mc0 = P##c.xy, mc1 = P##c.zw;                            \
            const f2 xd0 = P##d.xy, xd1 = P##d.zw;                            \
            f4v o4;                                                           \
            o4.xy = pkfma(CC1, X.yy, CC0 * X.xx);                             \
            const f2 e0 = pkfma(xb1, yv.yy, xb0 * yv.xx);                     \
            X += pkclip(pkfma(ma0, X.xx, pkfma(ma1, X.yy, e0)));              \
            o4.zw = pkfma(CC1, X.yy, CC0 * X.xx);                             \
            const f2 e1 = pkfma(xd1, yv.ww, xd0 * yv.zz);                     \
            X += pkclip(pkfma(mc0, X.xx, pkfma(mc1, X.yy, e1)));              \
            outTv[(size_t)(OG) * BROWS + b] = o4;                             \
        }

        for (int it = 0; it <= NCHUNK; ++it) {
            if (it > 0) {
                const int cc = it - 1;
                const float4* wbuf = wlds[cc & 1];
                const int ogc = cc * G_CHUNK;
                WLG(s0, 0) WLG(s1, 1) WLG(t0, 2) WLG(t1, 3)
                SB();
                for (int q = 0; q < G_CHUNK / 8; ++q) {
                    const int g = 8 * q;
                    const int og = ogc + g;
                    GRANC(s0, d0, og + 0) GRANC(s1, d1, og + 1) SB();
                    WLG(s0, g + 4) WLG(s1, g + 5) SB();
                    GRANC(t0, d2, og + 2) GRANC(t1, d3, og + 3) SB();
                    WLG(t0, g + 6) WLG(t1, g + 7) SB();
                    GRANC(s0, d4, og + 4) GRANC(s1, d5, og + 5) SB();
                    WLG(s0, g + 8) WLG(s1, g + 9) SB();
                    GRANC(t0, d6, og + 6) GRANC(t1, d7, og + 7) SB();
                    WLG(t0, g + 10) WLG(t1, g + 11) SB();
                }
            }
            __syncthreads();
        }
#undef GRANC
#undef WLG
    }
}

// ---------------- fallback: verified monolithic kernel --------------------
__global__ __launch_bounds__(64) void grnn_mono(
    const float* __restrict__ inp, const float* __restrict__ Am,
    const float* __restrict__ Cm, const float* __restrict__ Dm,
    float* __restrict__ out, int B)
{
    const int b = blockIdx.x * blockDim.x + threadIdx.x;
    if (b >= B) return;
    const float a00 = Am[0], a01 = Am[1], a10 = Am[2], a11 = Am[3];
    const float c00 = Cm[0], c01 = Cm[1], c10 = Cm[2], c11 = Cm[3];
    const float d00 = Dm[0], d01 = Dm[1], d10 = Dm[2], d11 = Dm[3];
    float x0 = 1.0f, x1 = 0.0f;
    float p00 = 1.0f, p01 = 0.0f, p10 = 0.0f, p11 = 1.0f;
    const float2* __restrict__ in2 = reinterpret_cast<const float2*>(inp) + (size_t)b * T_LEN;
    float2* __restrict__ out2 = reinterpret_cast<float2*>(out) + (size_t)b * T_LEN;
#pragma unroll 4
    for (int t = 0; t < T_LEN; ++t) {
        float2 o;
        o.x = (c00 * x0 + c01 * x1) * DT_C;
        o.y = (c10 * x0 + c11 * x1) * DT_C;
        out2[t] = o;
        const float xi00 = p00 * c00 + p01 * c01 + d00;
        const float xi01 = p00 * c10 + p01 * c11 + d10;
        const float xi10 = p10 * c00 + p11 * c01 + d01;
        const float xi11 = p10 * c10 + p11 * c11 + d11;
        const float m00 = a00 - (xi00 * c00 + xi01 * c10);
        const float m01 = a01 - (xi00 * c01 + xi01 * c11);
        const float m10 = a10 - (xi10 * c00 + xi11 * c10);
        const float m11 = a11 - (xi10 * c01 + xi11 * c11);
        const float2 dy = in2[t];
        float dx0 = (m00 * x0 + m01 * x1) * DT_C + xi00 * dy.x + xi01 * dy.y;
        float dx1 = (m10 * x0 + m11 * x1) * DT_C + xi10 * dy.x + xi11 * dy.y;
        x0 += clipf(dx0, -MAXU, MAXU);
        x1 += clipf(dx1, -MAXU, MAXU);
        const float g00 = a00*p00 + a01*p10 + p00*a00 + p01*a01 + d00 - (xi00*xi00 + xi01*xi01);
        const float g01 = a00*p01 + a01*p11 + p00*a10 + p01*a11 + d01 - (xi00*xi10 + xi01*xi11);
        const float g10 = a10*p00 + a11*p10 + p10*a00 + p11*a01 + d10 - (xi10*xi00 + xi11*xi01);
        const float g11 = a10*p01 + a11*p11 + p10*a10 + p11*a11 + d11 - (xi10*xi10 + xi11*xi11);
        p00 = clipf(p00 + g00 * DT_C, -1.0f, 1.0f);
        p01 = clipf(p01 + g01 * DT_C, -1.0f, 1.0f);
        p10 = clipf(p10 + g10 * DT_C, -1.0f, 1.0f);
        p11 = clipf(p11 + g11 * DT_C, -1.0f, 1.0f);
    }
}

extern "C" void kernel_launch(void* const* d_in, const int* in_sizes, int n_in,
                              void* d_out, int out_size, void* d_ws, size_t ws_size,
                              hipStream_t stream) {
    const float* inp = (const float*)d_in[0];
    const float* Am  = (const float*)d_in[1];
    const float* Cm  = (const float*)d_in[2];
    const float* Dm  = (const float*)d_in[3];
    float* out = (float*)d_out;
    const int B = in_sizes[0] / (T_LEN * 2);  // 512

    float4* inT  = (float4*)d_ws;                       // [T4][BROWS]
    float4* outT = inT + (size_t)T4 * BROWS;
    const size_t need_ws = (size_t)2 * T4 * BROWS * sizeof(float4);  // 64 MiB

    if (B == BROWS && d_ws != nullptr && ws_size >= need_ws) {
        // 1) transpose input [B][T4] -> [T4][B]
        hipLaunchKernelGGL(transpose_f4, dim3(T4 / 32, BROWS / 32), dim3(256),
                           0, stream,
                           reinterpret_cast<const float4*>(inp), inT,
                           BROWS, T4);
        // 2) fused producer/consumer scan, packed math + pinned rings
        hipLaunchKernelGGL(grnn_fused4, dim3(BROWS / 64), dim3(128), 0,
                           stream, inT, Am, Cm, Dm, outT);
        // 3) transpose output [T4][B] -> [B][T4]
        hipLaunchKernelGGL(transpose_f4, dim3(BROWS / 32, T4 / 32), dim3(256),
                           0, stream,
                           outT, reinterpret_cast<float4*>(out), T4, BROWS);
    } else {
        hipLaunchKernelGGL(grnn_mono, dim3((B + 63) / 64), dim3(64), 0, stream,
                           inp, Am, Cm, Dm, out, B);
    }
}

// Round 9
// 526.733 us; speedup vs baseline: 2.5164x; 2.5164x over previous
//
#include <hip/hip_runtime.h>

// GRNN scan: B=512 sequences, T=8192 steps. Round 19.
// R18 post-mortem: asm "+v" pins after loads force the WAIT at the pin
// point (volatile asm requires the value) -> every ring load became
// blocking; 3x regression. Pins only work on store SOURCES (R11), never on
// load RESULTS.
// R19: back to proven R16 structure (8 blocks, fused producer hidden) with
// two additive, mechanism-understood cuts to the consumer's 246 cyc/granule
// (~72 VALU + ~48 ds-issue + ~20 ld/st + waits):
//  (a) R17's packed math (proven correct, -26% VALU), 1 row/lane, 8 blocks
//      (R17's regression was the 4-block grid, not the math);
//  (b) xi-only W for the special path: producer writes ONLY Xi (1 f4/step);
//      consumer derives Mdt = fma(-dt, xi_col, adt_col) in registers ->
//      2 ds_read_b128/granule instead of 4 (-24 cyc issue, less lgkm wait,
//      +8 cyc derive), producer phase(ii)/LDS-writes/bank-conflicts halved.

#define DT_C 1e-3f
#define MAXU 0.1f
#define T_LEN 8192
#define T4 (T_LEN / 2)          // 4096 float4 granules (2 steps each)
#define CHUNK 256               // steps per chunk
#define G_CHUNK (CHUNK / 2)     // 128 granules per chunk
#define NCHUNK (T_LEN / CHUNK)  // 32
#define BROWS 512               // batch rows

typedef float f2 __attribute__((ext_vector_type(2)));
typedef float f4v __attribute__((ext_vector_type(4)));

__device__ __forceinline__ float clipf(float v, float lo, float hi) {
    return fminf(fmaxf(v, lo), hi);
}
__device__ __forceinline__ f2 pkfma(f2 a, f2 b, f2 c) {
    return __builtin_elementwise_fma(a, b, c);
}
__device__ __forceinline__ f2 pkclip(f2 v) {
    const f2 lo = {-MAXU, -MAXU}, hi = {MAXU, MAXU};
    return __builtin_elementwise_min(__builtin_elementwise_max(v, lo), hi);
}
#define SB() __builtin_amdgcn_sched_barrier(0)

// ---------------- tiled float4 transpose: src[rows][cols] -> dst[cols][rows]
__global__ __launch_bounds__(256) void transpose_f4(
    const float4* __restrict__ src, float4* __restrict__ dst,
    int rows, int cols)
{
    __shared__ float4 tile[32][33];
    const int tx = threadIdx.x & 31;
    const int ty = threadIdx.x >> 5;
    const int c0 = blockIdx.x * 32;
    const int r0 = blockIdx.y * 32;
#pragma unroll
    for (int i = 0; i < 32; i += 8)
        tile[ty + i][tx] = src[(size_t)(r0 + ty + i) * cols + (c0 + tx)];
    __syncthreads();
#pragma unroll
    for (int i = 0; i < 32; i += 8)
        dst[(size_t)(c0 + ty + i) * rows + (r0 + tx)] = tile[tx][ty + i];
}

// ============= fused scan: wave0 consumer (packed), wave1 producer ========
// inT/outT are [T4][BROWS] float4 (transposed layout, proven R12).
__global__ __launch_bounds__(128, 1) void grnn_fused5(
    const float4* __restrict__ inT, const float* __restrict__ Am,
    const float* __restrict__ Cm, const float* __restrict__ Dm,
    float4* __restrict__ outT)
{
    __shared__ float4 wlds[2][CHUNK * 2];   // 16 KB W double buffer
    __shared__ float4 sbnd[CHUNK / 8];      // 32 sub-boundaries (every 8 steps)
    const int tid = threadIdx.x;
    const int wv = tid >> 6;

    const float a00 = Am[0], a01 = Am[1], a10 = Am[2], a11 = Am[3];
    const float c00 = Cm[0], c01 = Cm[1], c10 = Cm[2], c11 = Cm[3];
    const float d00 = Dm[0], d01 = Dm[1], d10 = Dm[2], d11 = Dm[3];
    const bool special = (c00 == 1.f) && (c01 == 0.f) && (c10 == 0.f) &&
                         (c11 == 1.f) && (d01 == 0.f) && (d10 == 0.f);
    const float adt00 = a00 * DT_C, adt01 = a01 * DT_C;
    const float adt10 = a10 * DT_C, adt11 = a11 * DT_C;

    if (wv == 1) {
        // ===================== producer wave =============================
        const int lane = tid & 63;

        if (special) {
            // xi-space: u=p00+d00, w=p01, v=p11+d11 (== RSTEP_S algebra)
            const float K00 = 1.f + 2.f * adt00, A2dt01 = 2.f * adt01;
            const float K11 = 1.f + 2.f * adt11, A2dt10 = 2.f * adt10;
            const float K01 = 1.f + (a00 + a11) * DT_C;
            const float C0u = DT_C * d00 * (1.f - 2.f * a00);
            const float C0v = DT_C * d11 * (1.f - 2.f * a11);
            const float C1w = -(adt10 * d00 + adt01 * d11);

#define XSTEP()                                                               \
            {                                                                 \
                const float w2 = w * w;                                       \
                const float gu = fmaf(-DT_C, u, K00);                         \
                const float gv = fmaf(-DT_C, v, K11);                         \
                const float s  = u + v;                                       \
                const float ru = fmaf(A2dt01, w, fmaf(-DT_C, w2, C0u));       \
                const float rv = fmaf(A2dt10, w, fmaf(-DT_C, w2, C0v));       \
                const float gw = fmaf(-DT_C, s, K01);                         \
                const float rw = fmaf(adt10, u, fmaf(adt01, v, C1w));         \
                const float un = fmaf(u, gu, ru);                             \
                const float vn = fmaf(v, gv, rv);                             \
                const float wn = fmaf(w, gw, rw);                             \
                u = un; v = vn; w = wn;                                       \
            }

            float u = 1.f + d00, w = 0.f, v = 1.f + d11;  // P0=I
            for (int it = 0; it <= NCHUNK; ++it) {
                if (it < NCHUNK) {
                    // phase (i): serial 256 steps, sub-boundary every 8
                    if (lane == 0) {
                        for (int j = 0; j < CHUNK / 8; ++j) {
                            sbnd[j] = make_float4(u, w, v, 0.f);
                            XSTEP() XSTEP() XSTEP() XSTEP()
                            XSTEP() XSTEP() XSTEP() XSTEP()
                        }
                    }
                    asm volatile("s_waitcnt lgkmcnt(0)" ::: "memory");
                    SB();
                    __builtin_amdgcn_wave_barrier();
                    // phase (ii): 32 lanes x 8 steps -> XI ONLY (1 f4/step)
                    if (lane < CHUNK / 8) {
                        const float4 sb = sbnd[lane];
                        float u2 = sb.x, w2v = sb.y, v2 = sb.z;
                        float4* wdst = wlds[it & 1] + (lane * 8);
#pragma unroll
                        for (int k = 0; k < 8; ++k) {
                            wdst[k] = make_float4(u2, w2v, w2v, v2);
                            {
                                float u = u2, w = w2v, v = v2;
                                XSTEP()
                                u2 = u; w2v = w; v2 = v;
                            }
                        }
                    }
                }
                __syncthreads();
            }
#undef XSTEP
        } else {
            // generic path: full P, clips kept; writes mdt + xi (2 f4/step)
#define RSTEP_G()                                                             \
            {                                                                 \
                const float xi00 = p00*c00 + p01*c01 + d00;                   \
                const float xi01 = p00*c10 + p01*c11 + d10;                   \
                const float xi10 = p10*c00 + p11*c01 + d01;                   \
                const float xi11 = p10*c10 + p11*c11 + d11;                   \
                const float g00 = a00*p00 + a01*p10 + p00*a00 + p01*a01 + d00 - (xi00*xi00 + xi01*xi01); \
                const float g01 = a00*p01 + a01*p11 + p00*a10 + p01*a11 + d01 - (xi00*xi10 + xi01*xi11); \
                const float g10 = a10*p00 + a11*p10 + p10*a00 + p11*a01 + d10 - (xi10*xi00 + xi11*xi01); \
                const float g11 = a10*p01 + a11*p11 + p10*a10 + p11*a11 + d11 - (xi10*xi10 + xi11*xi11); \
                p00 = clipf(p00 + g00 * DT_C, -1.f, 1.f);                     \
                p01 = clipf(p01 + g01 * DT_C, -1.f, 1.f);                     \
                p10 = clipf(p10 + g10 * DT_C, -1.f, 1.f);                     \
                p11 = clipf(p11 + g11 * DT_C, -1.f, 1.f);                     \
            }
            float p00 = 1.f, p01 = 0.f, p10 = 0.f, p11 = 1.f;
            for (int it = 0; it <= NCHUNK; ++it) {
                if (it < NCHUNK) {
                    if (lane == 0) {
                        for (int j = 0; j < CHUNK / 8; ++j) {
                            sbnd[j] = make_float4(p00, p01, p10, p11);
                            RSTEP_G() RSTEP_G() RSTEP_G() RSTEP_G()
                            RSTEP_G() RSTEP_G() RSTEP_G() RSTEP_G()
                        }
                    }
                    asm volatile("s_waitcnt lgkmcnt(0)" ::: "memory");
                    SB();
                    __builtin_amdgcn_wave_barrier();
                    if (lane < CHUNK / 8) {
                        const float4 sb = sbnd[lane];
                        float p00 = sb.x, p01 = sb.y, p10 = sb.z, p11 = sb.w;
                        float4* wdst = wlds[it & 1] + 2 * (lane * 8);
#pragma unroll
                        for (int k = 0; k < 8; ++k) {
                            const float xi00 = p00*c00 + p01*c01 + d00;
                            const float xi01 = p00*c10 + p01*c11 + d10;
                            const float xi10 = p10*c00 + p11*c01 + d01;
                            const float xi11 = p10*c10 + p11*c11 + d11;
                            const float m00 = a00 - (xi00*c00 + xi01*c10);
                            const float m01 = a01 - (xi00*c01 + xi01*c11);
                            const float m10 = a10 - (xi10*c00 + xi11*c10);
                            const float m11 = a11 - (xi10*c01 + xi11*c11);
                            float4 mv, xv;
                            mv.x = m00 * DT_C; mv.y = m10 * DT_C;
                            mv.z = m01 * DT_C; mv.w = m11 * DT_C;
                            xv = make_float4(xi00, xi10, xi01, xi11);
                            wdst[2 * k]     = mv;
                            wdst[2 * k + 1] = xv;
                            RSTEP_G()
                        }
                    }
                }
                __syncthreads();
            }
#undef RSTEP_G
        }
    } else {
        // ======= consumer wave: 1 row/lane, packed math ==================
        const int lane = tid;
        const int b = blockIdx.x * 64 + lane;
        const f2 CC0 = {c00 * DT_C, c10 * DT_C};   // C column 0 * dt
        const f2 CC1 = {c01 * DT_C, c11 * DT_C};   // C column 1 * dt
        const f4v* __restrict__ inTv = reinterpret_cast<const f4v*>(inT);
        f4v* __restrict__ outTv = reinterpret_cast<f4v*>(outT);

        f2 X = {1.f, 0.f};
        // dy ring: 8-granule lookahead
        f4v d0 = inTv[(size_t)0 * BROWS + b], d1 = inTv[(size_t)1 * BROWS + b];
        f4v d2 = inTv[(size_t)2 * BROWS + b], d3 = inTv[(size_t)3 * BROWS + b];
        f4v d4 = inTv[(size_t)4 * BROWS + b], d5 = inTv[(size_t)5 * BROWS + b];
        f4v d6 = inTv[(size_t)6 * BROWS + b], d7 = inTv[(size_t)7 * BROWS + b];

        if (special) {
            // xi-only W: 2 ds_read_b128/granule; Mdt derived in registers
            const f2 ndt = {-DT_C, -DT_C};
            const f2 A0 = {adt00, adt10};   // A*dt column 0
            const f2 A1 = {adt01, adt11};   // A*dt column 1
            f4v s0a, s0b, s1a, s1b, t0a, t0b, t1a, t1b;

#define WLGS(P, G)                                                            \
            {                                                                 \
                const int gg = (G) < G_CHUNK ? (G) : (G_CHUNK - 1);           \
                const f4v* wp = reinterpret_cast<const f4v*>(wbuf + 2 * gg);  \
                P##a = wp[0]; P##b = wp[1];                                   \
            }

            // one granule = 2 steps. P##a/b = Xi step0/1 (u,w,w,v).
#define GRANCS(P, DJ, OG)                                                     \
            {                                                                 \
                const f4v yv = DJ;                                            \
                {                                                             \
                    const int nog = (OG) + 8;                                 \
                    const int rg = nog < T4 ? nog : (T4 - 1);                 \
                    DJ = inTv[(size_t)rg * BROWS + b];                        \
                }                                                             \
                const f2 xa0 = P##a.xy, xa1 = P##a.zw;                        \
                const f2 xb0 = P##b.xy, xb1 = P##b.zw;                        \
                const f2 ma0 = pkfma(ndt, xa0, A0);                           \
                const f2 ma1 = pkfma(ndt, xa1, A1);                           \
                const f2 mb0 = pkfma(ndt, xb0, A0);                           \
                const f2 mb1 = pkfma(ndt, xb1, A1);                           \
                f4v o4;                                                       \
                o4.xy = pkfma(CC1, X.yy, CC0 * X.xx);                         \
                const f2 e0 = pkfma(xa1, yv.yy, xa0 * yv.xx);                 \
                X += pkclip(pkfma(ma0, X.xx, pkfma(ma1, X.yy, e0)));          \
                o4.zw = pkfma(CC1, X.yy, CC0 * X.xx);                         \
                const f2 e1 = pkfma(xb1, yv.ww, xb0 * yv.zz);                 \
                X += pkclip(pkfma(mb0, X.xx, pkfma(mb1, X.yy, e1)));          \
                outTv[(size_t)(OG) * BROWS + b] = o4;                         \
            }

            for (int it = 0; it <= NCHUNK; ++it) {
                if (it > 0) {
                    const int cc = it - 1;
                    const float4* wbuf = wlds[cc & 1];
                    const int ogc = cc * G_CHUNK;
                    WLGS(s0, 0) WLGS(s1, 1) WLGS(t0, 2) WLGS(t1, 3)
                    SB();
                    for (int q = 0; q < G_CHUNK / 8; ++q) {
                        const int g = 8 * q;
                        const int og = ogc + g;
                        GRANCS(s0, d0, og + 0) GRANCS(s1, d1, og + 1) SB();
                        WLGS(s0, g + 4) WLGS(s1, g + 5) SB();
                        GRANCS(t0, d2, og + 2) GRANCS(t1, d3, og + 3) SB();
                        WLGS(t0, g + 6) WLGS(t1, g + 7) SB();
                        GRANCS(s0, d4, og + 4) GRANCS(s1, d5, og + 5) SB();
                        WLGS(s0, g + 8) WLGS(s1, g + 9) SB();
                        GRANCS(t0, d6, og + 6) GRANCS(t1, d7, og + 7) SB();
                        WLGS(t0, g + 10) WLGS(t1, g + 11) SB();
                    }
                }
                __syncthreads();
            }
#undef GRANCS
#undef WLGS
        } else {
            // generic: 4-read packed GRANC (R17, proven layout)
            f4v s0a, s0b, s0c, s0d, s1a, s1b, s1c, s1d;
            f4v t0a, t0b, t0c, t0d, t1a, t1b, t1c, t1d;

#define WLG(P, G)                                                             \
            {                                                                 \
                const int gg = (G) < G_CHUNK ? (G) : (G_CHUNK - 1);           \
                const f4v* wp = reinterpret_cast<const f4v*>(wbuf + 4 * gg);  \
                P##a = wp[0]; P##b = wp[1]; P##c = wp[2]; P##d = wp[3];       \
            }

#define GRANC(P, DJ, OG)                                                      \
            {                                                                 \
                const f4v yv = DJ;                                            \
                {                                                             \
                    const int nog = (OG) + 8;                                 \
                    const int rg = nog < T4 ? nog : (T4 - 1);                 \
                    DJ = inTv[(size_t)rg * BROWS + b];                        \
                }                                                             \
                const f2 ma0 = P##a.xy, ma1 = P##a.zw;                        \
                const f2 xb0 = P##b.xy, xb1 = P##b.zw;                        \
                const f2 mc0 = P##c.xy, mc1 = P##c.zw;                        \
                const f2 xd0 = P##d.xy, xd1 = P##d.zw;                        \
                f4v o4;                                                       \
                o4.xy = pkfma(CC1, X.yy, CC0 * X.xx);                         \
                const f2 e0 = pkfma(xb1, yv.yy, xb0 * yv.xx);                 \
                X += pkclip(pkfma(ma0, X.xx, pkfma(ma1, X.yy, e0)));          \
                o4.zw = pkfma(CC1, X.yy, CC0 * X.xx);                         \
                const f2 e1 = pkfma(xd1, yv.ww, xd0 * yv.zz);                 \
                X += pkclip(pkfma(mc0, X.xx, pkfma(mc1, X.yy, e1)));          \
                outTv[(size_t)(OG) * BROWS + b] = o4;                         \
            }

            for (int it = 0; it <= NCHUNK; ++it) {
                if (it > 0) {
                    const int cc = it - 1;
                    const float4* wbuf = wlds[cc & 1];
                    const int ogc = cc * G_CHUNK;
                    WLG(s0, 0) WLG(s1, 1) WLG(t0, 2) WLG(t1, 3)
                    SB();
                    for (int q = 0; q < G_CHUNK / 8; ++q) {
                        const int g = 8 * q;
                        const int og = ogc + g;
                        GRANC(s0, d0, og + 0) GRANC(s1, d1, og + 1) SB();
                        WLG(s0, g + 4) WLG(s1, g + 5) SB();
                        GRANC(t0, d2, og + 2) GRANC(t1, d3, og + 3) SB();
                        WLG(t0, g + 6) WLG(t1, g + 7) SB();
                        GRANC(s0, d4, og + 4) GRANC(s1, d5, og + 5) SB();
                        WLG(s0, g + 8) WLG(s1, g + 9) SB();
                        GRANC(t0, d6, og + 6) GRANC(t1, d7, og + 7) SB();
                        WLG(t0, g + 10) WLG(t1, g + 11) SB();
                    }
                }
                __syncthreads();
            }
#undef GRANC
#undef WLG
        }
    }
}

// ---------------- fallback: verified monolithic kernel --------------------
__global__ __launch_bounds__(64) void grnn_mono(
    const float* __restrict__ inp, const float* __restrict__ Am,
    const float* __restrict__ Cm, const float* __restrict__ Dm,
    float* __restrict__ out, int B)
{
    const int b = blockIdx.x * blockDim.x + threadIdx.x;
    if (b >= B) return;
    const float a00 = Am[0], a01 = Am[1], a10 = Am[2], a11 = Am[3];
    const float c00 = Cm[0], c01 = Cm[1], c10 = Cm[2], c11 = Cm[3];
    const float d00 = Dm[0], d01 = Dm[1], d10 = Dm[2], d11 = Dm[3];
    float x0 = 1.0f, x1 = 0.0f;
    float p00 = 1.0f, p01 = 0.0f, p10 = 0.0f, p11 = 1.0f;
    const float2* __restrict__ in2 = reinterpret_cast<const float2*>(inp) + (size_t)b * T_LEN;
    float2* __restrict__ out2 = reinterpret_cast<float2*>(out) + (size_t)b * T_LEN;
#pragma unroll 4
    for (int t = 0; t < T_LEN; ++t) {
        float2 o;
        o.x = (c00 * x0 + c01 * x1) * DT_C;
        o.y = (c10 * x0 + c11 * x1) * DT_C;
        out2[t] = o;
        const float xi00 = p00 * c00 + p01 * c01 + d00;
        const float xi01 = p00 * c10 + p01 * c11 + d10;
        const float xi10 = p10 * c00 + p11 * c01 + d01;
        const float xi11 = p10 * c10 + p11 * c11 + d11;
        const float m00 = a00 - (xi00 * c00 + xi01 * c10);
        const float m01 = a01 - (xi00 * c01 + xi01 * c11);
        const float m10 = a10 - (xi10 * c00 + xi11 * c10);
        const float m11 = a11 - (xi10 * c01 + xi11 * c11);
        const float2 dy = in2[t];
        float dx0 = (m00 * x0 + m01 * x1) * DT_C + xi00 * dy.x + xi01 * dy.y;
        float dx1 = (m10 * x0 + m11 * x1) * DT_C + xi10 * dy.x + xi11 * dy.y;
        x0 += clipf(dx0, -MAXU, MAXU);
        x1 += clipf(dx1, -MAXU, MAXU);
        const float g00 = a00*p00 + a01*p10 + p00*a00 + p01*a01 + d00 - (xi00*xi00 + xi01*xi01);
        const float g01 = a00*p01 + a01*p11 + p00*a10 + p01*a11 + d01 - (xi00*xi10 + xi01*xi11);
        const float g10 = a10*p00 + a11*p10 + p10*a00 + p11*a01 + d10 - (xi10*xi00 + xi11*xi01);
        const float g11 = a10*p01 + a11*p11 + p10*a10 + p11*a11 + d11 - (xi10*xi10 + xi11*xi11);
        p00 = clipf(p00 + g00 * DT_C, -1.0f, 1.0f);
        p01 = clipf(p01 + g01 * DT_C, -1.0f, 1.0f);
        p10 = clipf(p10 + g10 * DT_C, -1.0f, 1.0f);
        p11 = clipf(p11 + g11 * DT_C, -1.0f, 1.0f);
    }
}

extern "C" void kernel_launch(void* const* d_in, const int* in_sizes, int n_in,
                              void* d_out, int out_size, void* d_ws, size_t ws_size,
                              hipStream_t stream) {
    const float* inp = (const float*)d_in[0];
    const float* Am  = (const float*)d_in[1];
    const float* Cm  = (const float*)d_in[2];
    const float* Dm  = (const float*)d_in[3];
    float* out = (float*)d_out;
    const int B = in_sizes[0] / (T_LEN * 2);  // 512

    float4* inT  = (float4*)d_ws;                       // [T4][BROWS]
    float4* outT = inT + (size_t)T4 * BROWS;
    const size_t need_ws = (size_t)2 * T4 * BROWS * sizeof(float4);  // 64 MiB

    if (B == BROWS && d_ws != nullptr && ws_size >= need_ws) {
        // 1) transpose input [B][T4] -> [T4][B]
        hipLaunchKernelGGL(transpose_f4, dim3(T4 / 32, BROWS / 32), dim3(256),
                           0, stream,
                           reinterpret_cast<const float4*>(inp), inT,
                           BROWS, T4);
        // 2) fused producer/consumer scan, packed math + xi-only W
        hipLaunchKernelGGL(grnn_fused5, dim3(BROWS / 64), dim3(128), 0,
                           stream, inT, Am, Cm, Dm, outT);
        // 3) transpose output [T4][B] -> [B][T4]
        hipLaunchKernelGGL(transpose_f4, dim3(BROWS / 32, T4 / 32), dim3(256),
                           0, stream,
                           outT, reinterpret_cast<float4*>(out), T4, BROWS);
    } else {
        hipLaunchKernelGGL(grnn_mono, dim3((B + 63) / 64), dim3(64), 0, stream,
                           inp, Am, Cm, Dm, out, B);
    }
}